// Round 5
// baseline (190.061 us; speedup 1.0000x reference)
//
#include <hip/hip_runtime.h>
#include <math.h>

#define KS    31
#define PADV  15
#define IMG   320
#define NOUT  289          // valid centered outputs (i in [15, 304))
#define TB    8            // 8x8 output pixels per block
#define TROWS 38           // TB + KS - 1
#define TSTR  39           // padded LDS row stride (odd -> conflict-free)

__device__ __forceinline__ unsigned int ordkey(float f) {
    unsigned int b = __float_as_uint(f);
    return (b & 0x80000000u) ? ~b : (b | 0x80000000u);
}
__device__ __forceinline__ float ordval(unsigned int k) {
    unsigned int b = (k & 0x80000000u) ? (k & 0x7FFFFFFFu) : ~k;
    return __uint_as_float(b);
}

__global__ void init_mm(unsigned int* mm) {
    mm[0] = 0xFFFFFFFFu;   // running-min key
    mm[1] = 0u;            // running-max key
}

// 256 threads = 64 pixels x 4 row-parts. Part q handles rows q*8..q*8+7
// (row 31 statically masked to zero weight in the r==7 body).
__global__ __launch_bounds__(256, 4) void gabor_fast(
    const float* __restrict__ fp, const int* __restrict__ fmap,
    const int* __restrict__ tmap, float* __restrict__ out,
    unsigned int* __restrict__ mm)
{
    __shared__ float tile[TROWS * TSTR];
    const int bh = blockIdx.y * TB;
    const int bw = blockIdx.x * TB;
    const int tid = threadIdx.x;

    for (int i = tid; i < TROWS * TSTR; i += 256) {
        int r = i / TSTR, c = i - r * TSTR;
        int gr = bh + r, gc = bw + c;
        tile[i] = (gr < IMG && gc < IMG) ? fp[gr * IMG + gc] : 0.0f;
    }
    __syncthreads();

    const int pixel = tid >> 2, part = tid & 3;
    const int px = pixel & 7, py = pixel >> 3;
    const int oy = bh + py, ox = bw + px;
    const bool valid = (oy < NOUT) && (ox < NOUT);

    float acc0 = 0.0f, acc1 = 0.0f;
    if (valid) {
        const int iy = oy + PADV, ix = ox + PADV;
        const float th = ((float)tmap[iy * IMG + ix] / 180.0f) * 3.14159265358979323846f;
        const float f0 = 0.025f + 0.0015f * (float)fmap[iy * IMG + ix];
        float st, ct;
        sincosf(th, &st, &ct);
        const float nst = -st;
        const float fch = f0 * (1.0f / 45.0f);            // (f0/3)/half
        const float kE  = -0.0200374311f;                 // -log2(e)/72
        const float lastw = (part == 3) ? 0.0f : 1.0f;    // mask dy==31
        const int r0 = part * 8;

        #pragma unroll
        for (int r = 0; r < 8; ++r) {
            const int dy = r0 + r;
            const int dya = (r == 7 && dy > 30) ? 30 : dy;  // clamp addr only r==7
            const float y   = (float)(dy - PADV);
            const float yst = y * st, yct = y * ct;
            const float* trow = &tile[(py + dya) * TSTR + px];

            float tv[KS];
            #pragma unroll
            for (int c = 0; c < KS; ++c) tv[c] = trow[c];

            #pragma unroll
            for (int c = 0; c < KS; ++c) {
                const float x = (float)(c - PADV);
                float x_t = fmaf(x, ct,  yst);
                float y_t = fmaf(x, nst, yct);
                float g   = fmaf(0.04f, fabsf(y_t), 1.0f);    // 1 + 0.6|y_t|/15
                float gyt = g * y_t;
                float s2  = fmaf(x_t, x_t, gyt * gyt);
                float e   = __builtin_amdgcn_exp2f(s2 * kE);  // exp(-s2/72)
                float fl  = fmaf(fch, y_t, f0);
                float cc  = __builtin_amdgcn_cosf(fl * x_t);  // cos(2*pi*fl*x_t)
                float w   = e * cc;
                if (r == 7) w *= lastw;                        // static: only last row
                if (c & 1) acc1 = fmaf(tv[c], w, acc1);
                else       acc0 = fmaf(tv[c], w, acc0);
            }
        }
    }

    // combine the 4 row-parts (adjacent lanes) of each pixel
    float v = acc0 + acc1;
    v += __shfl_xor(v, 1, 64);
    v += __shfl_xor(v, 2, 64);

    float vmin = INFINITY, vmax = -INFINITY;
    if (valid && part == 0) {
        out[(oy + PADV) * IMG + (ox + PADV)] = v;
        vmin = v; vmax = v;
    }
    for (int off = 32; off; off >>= 1) {
        vmin = fminf(vmin, __shfl_down(vmin, off, 64));
        vmax = fmaxf(vmax, __shfl_down(vmax, off, 64));
    }
    if ((tid & 63) == 0) {
        atomicMin(&mm[0], ordkey(vmin));
        atomicMax(&mm[1], ordkey(vmax));
    }
}

__global__ __launch_bounds__(256) void border_copy(
    const float* __restrict__ fp, float* __restrict__ out,
    unsigned int* __restrict__ mm)
{
    int p = blockIdx.x * 256 + threadIdx.x;
    float vmin = INFINITY, vmax = -INFINITY;
    if (p < IMG * IMG) {
        int i = p / IMG, j = p - i * IMG;
        bool inner = (i >= PADV) && (i < PADV + NOUT) && (j >= PADV) && (j < PADV + NOUT);
        if (!inner) {
            float v = fp[p];
            out[p] = v;
            vmin = v; vmax = v;
        }
    }
    for (int off = 32; off; off >>= 1) {
        vmin = fminf(vmin, __shfl_down(vmin, off, 64));
        vmax = fmaxf(vmax, __shfl_down(vmax, off, 64));
    }
    if ((threadIdx.x & 63) == 0) {
        atomicMin(&mm[0], ordkey(vmin));
        atomicMax(&mm[1], ordkey(vmax));
    }
}

__global__ __launch_bounds__(256) void finalize(
    float* __restrict__ out, const unsigned int* __restrict__ mm)
{
    int p = blockIdx.x * 256 + threadIdx.x;
    if (p >= IMG * IMG) return;
    float mn = ordval(mm[0]);
    float mx = ordval(mm[1]) - mn;       // max(out - min) == max0 - min0
    float v  = out[p] - mn;
    if (mx != 0.0f) v = v / mx * 100.0f;
    out[p] = (v > 55.0f) ? 100.0f : 0.0f;
}

extern "C" void kernel_launch(void* const* d_in, const int* in_sizes, int n_in,
                              void* d_out, int out_size, void* d_ws, size_t ws_size,
                              hipStream_t stream) {
    const float* fp   = (const float*)d_in[0];
    const int*   fmap = (const int*)d_in[1];
    const int*   tmap = (const int*)d_in[2];
    float* out = (float*)d_out;
    unsigned int* mm = (unsigned int*)d_ws;

    hipLaunchKernelGGL(init_mm, dim3(1), dim3(1), 0, stream, mm);

    dim3 g((NOUT + TB - 1) / TB, (NOUT + TB - 1) / TB);   // 37 x 37
    hipLaunchKernelGGL(gabor_fast, g, dim3(256), 0, stream, fp, fmap, tmap, out, mm);

    int nblk = (IMG * IMG + 255) / 256;
    hipLaunchKernelGGL(border_copy, dim3(nblk), dim3(256), 0, stream, fp, out, mm);
    hipLaunchKernelGGL(finalize,    dim3(nblk), dim3(256), 0, stream, out, mm);
}